// Round 2
// baseline (3157.236 us; speedup 1.0000x reference)
//
#include <hip/hip_runtime.h>
#include <cstdint>
#include <cstddef>

// Problem constants
#define EDIM 256
#define VDIM 8192
#define NPIX 16384   // B*H*W

// ---------------------------------------------------------------------------
// Exact emulation of numpy pairwise_sum for a contiguous block of 128 floats
// of x[i]*x[i] (mul rounded f32 first, then summed):
//   r[0..7] = a[0..7]; for i=8,16,...,120: r[j] += a[i+j];
//   res = ((r0+r1)+(r2+r3)) + ((r4+r5)+(r6+r7))
// ---------------------------------------------------------------------------
__device__ __forceinline__ float np_sqpair128(const float* __restrict__ z) {
    float r[8];
#pragma unroll
    for (int j = 0; j < 8; ++j) r[j] = __fmul_rn(z[j], z[j]);
    for (int i = 8; i < 128; i += 8) {
#pragma unroll
        for (int j = 0; j < 8; ++j)
            r[j] = __fadd_rn(r[j], __fmul_rn(z[i + j], z[i + j]));
    }
    float t01 = __fadd_rn(r[0], r[1]), t23 = __fadd_rn(r[2], r[3]);
    float t45 = __fadd_rn(r[4], r[5]), t67 = __fadd_rn(r[6], r[7]);
    return __fadd_rn(__fadd_rn(t01, t23), __fadd_rn(t45, t67));
}

// numpy np.sum(z*z) for n=256: pairwise splits 256 -> 128 + 128
__device__ __forceinline__ float np_sqnorm256(const float* __restrict__ z) {
    return __fadd_rn(np_sqpair128(z), np_sqpair128(z + 128));
}

// ---------------- Stage 1: z32 = x @ W_pre^T + b_pre, np.einsum f32 semantics ----------------
// Sequential c=0..255 accumulation, separate mul+add (no FMA), then separate +b_pre.
__global__ __launch_bounds__(256) void pre_quant(const float* __restrict__ x,
                                                 const float* __restrict__ Wpre,
                                                 const float* __restrict__ bpre,
                                                 float* __restrict__ z32) {
    __shared__ float xs[16][257];   // [pix][c]
    __shared__ float wt[256][33];   // [e][c-chunk 32]
    int n0 = blockIdx.x * 16;
    int b = n0 >> 8, pix0 = n0 & 255;
    int t = threadIdx.x;

#pragma unroll
    for (int i = 0; i < 16; ++i) {
        int f = t + i * 256;
        int c = f >> 4, p = f & 15;
        xs[p][c] = x[(size_t)b * 65536 + (size_t)c * 256 + pix0 + p];
    }

    int p = t & 15, eb = (t >> 4) * 16;
    float acc[16];
#pragma unroll
    for (int i = 0; i < 16; ++i) acc[i] = 0.0f;

    for (int c0 = 0; c0 < 256; c0 += 32) {
        __syncthreads();
#pragma unroll
        for (int i = 0; i < 32; ++i) {
            int f = t + i * 256;
            int e = f >> 5, c = f & 31;
            wt[e][c] = Wpre[(size_t)e * 256 + c0 + c];
        }
        __syncthreads();
        for (int c = 0; c < 32; ++c) {
            float xv = xs[p][c0 + c];
#pragma unroll
            for (int i = 0; i < 16; ++i)
                acc[i] = __fadd_rn(acc[i], __fmul_rn(xv, wt[eb + i][c]));
        }
    }
#pragma unroll
    for (int i = 0; i < 16; ++i)
        z32[(size_t)(n0 + p) * 256 + eb + i] = __fadd_rn(acc[i], bpre[eb + i]);
}

// ---------------- Stage 2a/2b: row norms (np pairwise semantics) ----------------
__global__ __launch_bounds__(256) void row_norms(const float* __restrict__ z32,
                                                 float* __restrict__ A32) {
    int n = blockIdx.x * 256 + threadIdx.x;
    A32[n] = np_sqnorm256(z32 + (size_t)n * 256);
}

__global__ __launch_bounds__(256) void cb_norms(const float* __restrict__ cb,
                                                float* __restrict__ C32) {
    int v = blockIdx.x * 256 + threadIdx.x;
    C32[v] = np_sqnorm256(cb + (size_t)v * 256);
}

// ---------------- Stage 3: d = (A - 2*B) + C in f32, argmin first-min ----------------
// B via strictly ascending-k FMA chain (sgemm micro-kernel semantics).
// Block = 32 rows, 256 threads = 64 v-threads x 4 row-groups; thread tile 4v x 8r.
__global__ __launch_bounds__(256) void assign_tokens(const float* __restrict__ z32,
                                                     const float* __restrict__ cb,
                                                     const float* __restrict__ A32,
                                                     const float* __restrict__ C32,
                                                     int* __restrict__ tok_i,
                                                     float* __restrict__ tok_f) {
    __shared__ __align__(16) float zs[32][256];   // 32 KiB
    __shared__ float sm[32][64];                  // 8 KiB
    __shared__ int   im[32][64];                  // 8 KiB
    int n0 = blockIdx.x * 32;
    int t = threadIdx.x;

    for (int i = 0; i < 32; ++i)
        zs[i][t] = z32[(size_t)(n0 + i) * 256 + t];
    __syncthreads();

    int v_t = t & 63, r_g = t >> 6;
    float Arow[8];
#pragma unroll
    for (int rr = 0; rr < 8; ++rr) Arow[rr] = A32[n0 + r_g * 8 + rr];

    float s1[8]; int i1[8];
#pragma unroll
    for (int rr = 0; rr < 8; ++rr) { s1[rr] = 1e30f; i1[rr] = 0; }

    for (int vb = 0; vb < VDIM; vb += 256) {
        int vbase = vb + v_t * 4;
        float acc[4][8];
#pragma unroll
        for (int k = 0; k < 4; ++k)
#pragma unroll
            for (int rr = 0; rr < 8; ++rr) acc[k][rr] = 0.0f;

        for (int c0 = 0; c0 < 256; c0 += 4) {
            float4 zr[8];
#pragma unroll
            for (int rr = 0; rr < 8; ++rr)
                zr[rr] = *(const float4*)&zs[r_g * 8 + rr][c0];
#pragma unroll
            for (int k = 0; k < 4; ++k) {
                float4 cv = *(const float4*)&cb[(size_t)(vbase + k) * 256 + c0];
#pragma unroll
                for (int rr = 0; rr < 8; ++rr) {
                    // strictly ascending k within the chain: c0, c0+1, c0+2, c0+3
                    acc[k][rr] = __fmaf_rn(cv.x, zr[rr].x, acc[k][rr]);
                    acc[k][rr] = __fmaf_rn(cv.y, zr[rr].y, acc[k][rr]);
                    acc[k][rr] = __fmaf_rn(cv.z, zr[rr].z, acc[k][rr]);
                    acc[k][rr] = __fmaf_rn(cv.w, zr[rr].w, acc[k][rr]);
                }
            }
        }
#pragma unroll
        for (int k = 0; k < 4; ++k) {
            int v = vbase + k;
            float Cv = C32[v];
#pragma unroll
            for (int rr = 0; rr < 8; ++rr) {
                // d = (A - 2*B) + C, each op f32-rounded — matches np expression
                float d = __fadd_rn(__fsub_rn(Arow[rr], __fmul_rn(2.0f, acc[k][rr])), Cv);
                if (d < s1[rr] || (d == s1[rr] && v < i1[rr])) { s1[rr] = d; i1[rr] = v; }
            }
        }
    }

#pragma unroll
    for (int rr = 0; rr < 8; ++rr) {
        int r = r_g * 8 + rr;
        sm[r][v_t] = s1[rr]; im[r][v_t] = i1[rr];
    }
    __syncthreads();

    if (t < 32) {
        float bs = 1e30f; int bi = 0x7fffffff;
        for (int j = 0; j < 64; ++j) {
            float s = sm[t][j]; int v = im[t][j];
            if (s < bs || (s == bs && v < bi)) { bs = s; bi = v; }
        }
        tok_i[n0 + t] = bi;
        tok_f[n0 + t] = (float)bi;
    }
}

// ---------------- Stage 4: rec = codebook[tok] @ W_post^T + b_post (BCHW) ----------------
__global__ __launch_bounds__(256) void post_quant(const float* __restrict__ cb,
                                                  const float* __restrict__ Wpost,
                                                  const float* __restrict__ bpost,
                                                  const int* __restrict__ tok,
                                                  float* __restrict__ rec) {
    __shared__ float zq[16][257];   // [pix][e]
    __shared__ float wt[256][33];   // [cc][e-chunk 32]
    int n0 = blockIdx.x * 16;
    int b = n0 >> 8, pix0 = n0 & 255;
    int t = threadIdx.x;

    for (int p = 0; p < 16; ++p) {
        int tv = tok[n0 + p];
        zq[p][t] = cb[(size_t)tv * 256 + t];
    }

    int p = t & 15, ccb = (t >> 4) * 16;
    float acc[16];
#pragma unroll
    for (int i = 0; i < 16; ++i) acc[i] = bpost[ccb + i];

    for (int e0 = 0; e0 < 256; e0 += 32) {
        __syncthreads();
#pragma unroll
        for (int i = 0; i < 32; ++i) {
            int f = t + i * 256;
            int cc = f >> 5, e = f & 31;
            wt[cc][e] = Wpost[(size_t)cc * 256 + e0 + e];
        }
        __syncthreads();
        for (int e = 0; e < 32; ++e) {
            float xz = zq[p][e0 + e];
#pragma unroll
            for (int i = 0; i < 16; ++i)
                acc[i] += wt[ccb + i][e] * xz;
        }
    }
#pragma unroll
    for (int i = 0; i < 16; ++i)
        rec[(size_t)b * 65536 + (size_t)(ccb + i) * 256 + pix0 + p] = acc[i];
}

// ---------------- Launch ----------------
extern "C" void kernel_launch(void* const* d_in, const int* in_sizes, int n_in,
                              void* d_out, int out_size, void* d_ws, size_t ws_size,
                              hipStream_t stream) {
    const float* x     = (const float*)d_in[0];
    const float* Wpre  = (const float*)d_in[1];
    const float* bpre  = (const float*)d_in[2];
    const float* cb    = (const float*)d_in[3];
    const float* Wpost = (const float*)d_in[4];
    const float* bpost = (const float*)d_in[5];

    float* out   = (float*)d_out;
    float* rec   = out;                // 4,194,304 floats
    float* tok_f = out + 4194304;      // 16,384 floats

    // z32 (16,777,216 B) lives in the rec region of d_out; post_quant
    // overwrites it AFTER assign_tokens has consumed it (stream-ordered).
    float* z32 = rec;

    char* ws = (char*)d_ws;
    float* A32   = (float*)ws;              // 64 KiB
    float* C32   = (float*)(ws + 65536);    // 32 KiB
    int*   tok_i = (int*)(ws + 98304);      // 64 KiB

    pre_quant<<<NPIX / 16, 256, 0, stream>>>(x, Wpre, bpre, z32);
    row_norms<<<NPIX / 256, 256, 0, stream>>>(z32, A32);
    cb_norms<<<VDIM / 256, 256, 0, stream>>>(cb, C32);
    assign_tokens<<<NPIX / 32, 256, 0, stream>>>(z32, cb, A32, C32, tok_i, tok_f);
    post_quant<<<NPIX / 16, 256, 0, stream>>>(cb, Wpost, bpost, tok_i, rec);
}

// Round 3
// 562.899 us; speedup vs baseline: 5.6089x; 5.6089x over previous
//
#include <hip/hip_runtime.h>
#include <cstdint>
#include <cstddef>

#define EDIM 256
#define VDIM 8192
#define NPIX 16384

typedef __attribute__((ext_vector_type(8))) short          bf16x8;
typedef __attribute__((ext_vector_type(8))) unsigned short u16x8;
typedef __attribute__((ext_vector_type(4))) float          f32x4;

// RNE float->bf16 (finite inputs)
__device__ __forceinline__ unsigned short f2bf(float x) {
    unsigned int u = __float_as_uint(x);
    return (unsigned short)((u + 0x7fffu + ((u >> 16) & 1u)) >> 16);
}

// ---------- numpy pairwise sum-of-squares (exact semantics, verified r2) ----------
__device__ __forceinline__ float np_sqpair128(const float* __restrict__ z) {
    float r[8];
#pragma unroll
    for (int j = 0; j < 8; ++j) r[j] = __fmul_rn(z[j], z[j]);
    for (int i = 8; i < 128; i += 8) {
#pragma unroll
        for (int j = 0; j < 8; ++j)
            r[j] = __fadd_rn(r[j], __fmul_rn(z[i + j], z[i + j]));
    }
    float t01 = __fadd_rn(r[0], r[1]), t23 = __fadd_rn(r[2], r[3]);
    float t45 = __fadd_rn(r[4], r[5]), t67 = __fadd_rn(r[6], r[7]);
    return __fadd_rn(__fadd_rn(t01, t23), __fadd_rn(t45, t67));
}
__device__ __forceinline__ float np_sqnorm256(const float* __restrict__ z) {
    return __fadd_rn(np_sqpair128(z), np_sqpair128(z + 128));
}

// ---------------- Stage 1: z32 = x @ W_pre^T + b_pre (np einsum f32 semantics) ----------------
__global__ __launch_bounds__(256) void pre_quant(const float* __restrict__ x,
                                                 const float* __restrict__ Wpre,
                                                 const float* __restrict__ bpre,
                                                 float* __restrict__ z32) {
    __shared__ float xs[16][257];
    __shared__ float wt[256][33];
    int n0 = blockIdx.x * 16;
    int b = n0 >> 8, pix0 = n0 & 255;
    int t = threadIdx.x;
#pragma unroll
    for (int i = 0; i < 16; ++i) {
        int f = t + i * 256;
        int c = f >> 4, p = f & 15;
        xs[p][c] = x[(size_t)b * 65536 + (size_t)c * 256 + pix0 + p];
    }
    int p = t & 15, eb = (t >> 4) * 16;
    float acc[16];
#pragma unroll
    for (int i = 0; i < 16; ++i) acc[i] = 0.0f;
    for (int c0 = 0; c0 < 256; c0 += 32) {
        __syncthreads();
#pragma unroll
        for (int i = 0; i < 32; ++i) {
            int f = t + i * 256;
            int e = f >> 5, c = f & 31;
            wt[e][c] = Wpre[(size_t)e * 256 + c0 + c];
        }
        __syncthreads();
        for (int c = 0; c < 32; ++c) {
            float xv = xs[p][c0 + c];
#pragma unroll
            for (int i = 0; i < 16; ++i)
                acc[i] = __fadd_rn(acc[i], __fmul_rn(xv, wt[eb + i][c]));
        }
    }
#pragma unroll
    for (int i = 0; i < 16; ++i)
        z32[(size_t)(n0 + p) * 256 + eb + i] = __fadd_rn(acc[i], bpre[eb + i]);
}

// ---------------- norms ----------------
__global__ __launch_bounds__(256) void row_norms(const float* __restrict__ z32,
                                                 float* __restrict__ A32) {
    int n = blockIdx.x * 256 + threadIdx.x;
    A32[n] = np_sqnorm256(z32 + (size_t)n * 256);
}
__global__ __launch_bounds__(256) void cb_norms(const float* __restrict__ cb,
                                                float* __restrict__ C32) {
    int v = blockIdx.x * 256 + threadIdx.x;
    C32[v] = np_sqnorm256(cb + (size_t)v * 256);
}

// ---------------- f32 -> bf16 convert (vectorized, 8/thread) ----------------
__global__ __launch_bounds__(256) void to_bf16(const float* __restrict__ in,
                                               unsigned short* __restrict__ out, int n8) {
    int i = blockIdx.x * 256 + threadIdx.x;
    if (i >= n8) return;
    const float4* pp = (const float4*)in + (size_t)i * 2;
    float4 a = pp[0], b = pp[1];
    u16x8 o;
    o[0] = f2bf(a.x); o[1] = f2bf(a.y); o[2] = f2bf(a.z); o[3] = f2bf(a.w);
    o[4] = f2bf(b.x); o[5] = f2bf(b.y); o[6] = f2bf(b.z); o[7] = f2bf(b.w);
    *((u16x8*)out + i) = o;
}

// ---------------- Stage 2: bf16-MFMA screen -> top-8 candidates per row ----------------
// Block: 512 thr = 8 waves. Rows/block = 64: wave w -> row-group g=w>>1 (16 rows),
// v-half h=w&1 (4096 v). cb staged in LDS (swizzled), z frags in registers.
__device__ __forceinline__ void stage_load(const unsigned short* __restrict__ cbb,
                                           int ci, int t, u16x8 rg[4]) {
#pragma unroll
    for (int q = 0; q < 4; ++q) {
        int doff = q * 8192 + t * 16;
        int half = doff >> 14, r = doff & 16383, vl = r >> 9, inrow = r & 511;
        int vglob = half * 4096 + ci * 32 + vl;
        rg[q] = *(const u16x8*)((const char*)cbb + (size_t)vglob * 512 + (inrow ^ ((vl & 7) << 4)));
    }
}
__device__ __forceinline__ void stage_write(char* __restrict__ buf, int t, const u16x8 rg[4]) {
#pragma unroll
    for (int q = 0; q < 4; ++q)
        *(u16x8*)(buf + q * 8192 + t * 16) = rg[q];
}

#define UPD(ACC, CN, VIDX) do {                                            \
    float tsc = __fmaf_rn(-0.5f, (CN), (ACC));                             \
    if (tsc > thr) {                                                       \
        float mv = s8[0]; int pos = 0;                                     \
        _Pragma("unroll")                                                  \
        for (int j = 1; j < 8; ++j) if (s8[j] < mv) { mv = s8[j]; pos = j; } \
        _Pragma("unroll")                                                  \
        for (int j = 0; j < 8; ++j) if (j == pos) { s8[j] = tsc; v8[j] = (VIDX); } \
        mv = s8[0];                                                        \
        _Pragma("unroll")                                                  \
        for (int j = 1; j < 8; ++j) mv = fminf(mv, s8[j]);                 \
        thr = mv;                                                          \
    }                                                                      \
} while (0)

__global__ __launch_bounds__(512, 2) void screen_topk(const unsigned short* __restrict__ zb,
                                                      const unsigned short* __restrict__ cbb,
                                                      const float* __restrict__ C32,
                                                      int* __restrict__ cand) {
    __shared__ __align__(16) char lds[2][32768];   // 2 bufs x [2 half][32 v][512 B]
    int t = threadIdx.x;
    int w = t >> 6, l = t & 63;
    int g = w >> 1, h = w & 1;
    int rbase = blockIdx.x * 64 + g * 16;

    // z B-fragments: lane l holds z[rbase+(l&15)][ks*32 + (l>>4)*8 .. +7]
    bf16x8 zf[8];
    {
        const unsigned short* zr = zb + (size_t)(rbase + (l & 15)) * 256 + (l >> 4) * 8;
#pragma unroll
        for (int ks = 0; ks < 8; ++ks)
            zf[ks] = *(const bf16x8*)(zr + ks * 32);
    }

    float s8[8]; int v8[8]; float thr = -3e38f;
#pragma unroll
    for (int j = 0; j < 8; ++j) { s8[j] = -3e38f; v8[j] = 0x7fffffff; }

    u16x8 rg[4];
    stage_load(cbb, 0, t, rg);
    stage_write(lds[0], t, rg);
    __syncthreads();

    int kb = (l >> 4) * 16;        // k byte base within 64B k-step
    int sw = (l & 7) << 4;         // XOR swizzle
    const char* a0base;

    for (int ci = 0; ci < 128; ++ci) {
        int cur = ci & 1;
        if (ci < 127) stage_load(cbb, ci + 1, t, rg);

        const char* buf = lds[cur] + h * 16384;
        a0base = buf + (size_t)(l & 15) * 512;
        f32x4 acc0 = {0.f, 0.f, 0.f, 0.f}, acc1 = {0.f, 0.f, 0.f, 0.f};
#pragma unroll
        for (int ks = 0; ks < 8; ++ks) {
            int off = (ks * 64 + kb) ^ sw;
            bf16x8 af0 = *(const bf16x8*)(a0base + off);
            bf16x8 af1 = *(const bf16x8*)(a0base + 8192 + off);   // +16 v rows * 512B
            acc0 = __builtin_amdgcn_mfma_f32_16x16x32_bf16(af0, zf[ks], acc0, 0, 0, 0);
            acc1 = __builtin_amdgcn_mfma_f32_16x16x32_bf16(af1, zf[ks], acc1, 0, 0, 0);
        }
        int vb0 = h * 4096 + ci * 32 + (l >> 4) * 4;
        float4 c0 = *(const float4*)(C32 + vb0);
        float4 c1 = *(const float4*)(C32 + vb0 + 16);
        UPD(acc0[0], c0.x, vb0 + 0); UPD(acc0[1], c0.y, vb0 + 1);
        UPD(acc0[2], c0.z, vb0 + 2); UPD(acc0[3], c0.w, vb0 + 3);
        UPD(acc1[0], c1.x, vb0 + 16); UPD(acc1[1], c1.y, vb0 + 17);
        UPD(acc1[2], c1.z, vb0 + 18); UPD(acc1[3], c1.w, vb0 + 19);

        if (ci < 127) stage_write(lds[cur ^ 1], t, rg);
        __syncthreads();
    }

    // ---- merge: 2 waves x 4 lanes x 8 entries = 64 entries per row ----
    float* ms = (float*)&lds[0][0];                 // [64 rows][64]
    int*   mi = (int*)(&lds[0][0] + 16384);         // [64 rows][64]
    int rloc = g * 16 + (l & 15);
    int ebase = h * 32 + (l >> 4) * 8;
#pragma unroll
    for (int j = 0; j < 8; ++j) {
        ms[rloc * 64 + ebase + j] = s8[j];
        mi[rloc * 64 + ebase + j] = v8[j];
    }
    __syncthreads();
    if (t < 64) {
        int base = t * 64;
        for (int k = 0; k < 8; ++k) {
            float best = -3e38f; int bv = 0x7fffffff, be = 0;
            for (int e = 0; e < 64; ++e) {
                float s = ms[base + e]; int vv = mi[base + e];
                if (s > best || (s == best && vv < bv)) { best = s; bv = vv; be = e; }
            }
            cand[(size_t)(blockIdx.x * 64 + t) * 8 + k] = bv;
            ms[base + be] = -3e38f;
        }
    }
}

// ---------------- Stage 3: exact np-f32 re-rank of 8 candidates ----------------
__global__ __launch_bounds__(256) void rerank(const float* __restrict__ z32,
                                              const float* __restrict__ cb,
                                              const float* __restrict__ A32,
                                              const float* __restrict__ C32,
                                              const int* __restrict__ cand,
                                              int* __restrict__ tok_i,
                                              float* __restrict__ tok_f) {
    int t = blockIdx.x * 256 + threadIdx.x;
    int row = t >> 3, j = t & 7;
    int v = cand[(size_t)row * 8 + j];
    const float* zr = z32 + (size_t)row * 256;
    const float* cr = cb + (size_t)v * 256;
    float s = 0.0f;
#pragma unroll 8
    for (int k = 0; k < 256; ++k)
        s = __fmaf_rn(cr[k], zr[k], s);   // strictly ascending k — matches r2 chain
    float d = __fadd_rn(__fsub_rn(A32[row], __fmul_rn(2.0f, s)), C32[v]);
#pragma unroll
    for (int off = 4; off > 0; off >>= 1) {
        float d2 = __shfl_xor(d, off, 8);
        int   v2 = __shfl_xor(v, off, 8);
        if (d2 < d || (d2 == d && v2 < v)) { d = d2; v = v2; }
    }
    if (j == 0) { tok_i[row] = v; tok_f[row] = (float)v; }
}

// ---------------- Stage 4: rec = codebook[tok] @ W_post^T + b_post ----------------
__global__ __launch_bounds__(256) void post_quant(const float* __restrict__ cb,
                                                  const float* __restrict__ Wpost,
                                                  const float* __restrict__ bpost,
                                                  const int* __restrict__ tok,
                                                  float* __restrict__ rec) {
    __shared__ float zq[16][257];
    __shared__ float wt[256][33];
    int n0 = blockIdx.x * 16;
    int b = n0 >> 8, pix0 = n0 & 255;
    int t = threadIdx.x;
    for (int p = 0; p < 16; ++p) {
        int tv = tok[n0 + p];
        zq[p][t] = cb[(size_t)tv * 256 + t];
    }
    int p = t & 15, ccb = (t >> 4) * 16;
    float acc[16];
#pragma unroll
    for (int i = 0; i < 16; ++i) acc[i] = bpost[ccb + i];
    for (int e0 = 0; e0 < 256; e0 += 32) {
        __syncthreads();
#pragma unroll
        for (int i = 0; i < 32; ++i) {
            int f = t + i * 256;
            int cc = f >> 5, e = f & 31;
            wt[cc][e] = Wpost[(size_t)cc * 256 + e0 + e];
        }
        __syncthreads();
        for (int e = 0; e < 32; ++e) {
            float xz = zq[p][e0 + e];
#pragma unroll
            for (int i = 0; i < 16; ++i)
                acc[i] += wt[ccb + i][e] * xz;
        }
    }
#pragma unroll
    for (int i = 0; i < 16; ++i)
        rec[(size_t)b * 65536 + (size_t)(ccb + i) * 256 + pix0 + p] = acc[i];
}

// ---------------- Launch ----------------
extern "C" void kernel_launch(void* const* d_in, const int* in_sizes, int n_in,
                              void* d_out, int out_size, void* d_ws, size_t ws_size,
                              hipStream_t stream) {
    const float* x     = (const float*)d_in[0];
    const float* Wpre  = (const float*)d_in[1];
    const float* bpre  = (const float*)d_in[2];
    const float* cb    = (const float*)d_in[3];
    const float* Wpost = (const float*)d_in[4];
    const float* bpost = (const float*)d_in[5];

    float* out   = (float*)d_out;
    float* rec   = out;
    float* tok_f = out + 4194304;
    float* z32   = rec;   // z lives in rec region until post_quant overwrites it

    char* ws = (char*)d_ws;
    float*          A32   = (float*)ws;                       // 64 KiB
    float*          C32   = (float*)(ws + 65536);             // 32 KiB
    int*            tok_i = (int*)(ws + 98304);               // 64 KiB
    int*            cand  = (int*)(ws + 163840);              // 512 KiB
    unsigned short* zbb   = (unsigned short*)(ws + 1048576);  // 8 MiB
    unsigned short* cbb   = (unsigned short*)(ws + 9437184);  // 4 MiB

    pre_quant<<<NPIX / 16, 256, 0, stream>>>(x, Wpre, bpre, z32);
    to_bf16<<<(NPIX * 256 / 8) / 256, 256, 0, stream>>>(z32, zbb, NPIX * 256 / 8);
    to_bf16<<<(VDIM * 256 / 8) / 256, 256, 0, stream>>>(cb, cbb, VDIM * 256 / 8);
    row_norms<<<NPIX / 256, 256, 0, stream>>>(z32, A32);
    cb_norms<<<VDIM / 256, 256, 0, stream>>>(cb, C32);
    screen_topk<<<NPIX / 64, 512, 0, stream>>>(zbb, cbb, C32, cand);
    rerank<<<NPIX * 8 / 256, 256, 0, stream>>>(z32, cb, A32, C32, cand, tok_i, tok_f);
    post_quant<<<NPIX / 16, 256, 0, stream>>>(cb, Wpost, bpost, tok_i, rec);
}

// Round 4
// 547.092 us; speedup vs baseline: 5.7709x; 1.0289x over previous
//
#include <hip/hip_runtime.h>
#include <cstdint>
#include <cstddef>

#define EDIM 256
#define VDIM 8192
#define NPIX 16384

typedef __attribute__((ext_vector_type(8))) short          bf16x8;
typedef __attribute__((ext_vector_type(8))) unsigned short u16x8;
typedef __attribute__((ext_vector_type(4))) float          f32x4;
typedef __attribute__((ext_vector_type(2))) float          f32x2;

// RNE float->bf16
__device__ __forceinline__ unsigned short f2bf(float x) {
    unsigned int u = __float_as_uint(x);
    return (unsigned short)((u + 0x7fffu + ((u >> 16) & 1u)) >> 16);
}

__device__ __forceinline__ void gload_lds16(const void* gsrc, void* ldst) {
#if defined(__has_builtin) && __has_builtin(__builtin_amdgcn_global_load_lds)
    __builtin_amdgcn_global_load_lds(
        (const __attribute__((address_space(1))) unsigned int*)gsrc,
        (__attribute__((address_space(3))) unsigned int*)ldst, 16, 0, 0);
#else
    *(float4*)ldst = *(const float4*)gsrc;   // correct fallback (slower)
#endif
}

// ---------- numpy pairwise sum-of-squares (exact semantics, verified r2) ----------
__device__ __forceinline__ float np_sqpair128(const float* __restrict__ z) {
    float r[8];
#pragma unroll
    for (int j = 0; j < 8; ++j) r[j] = __fmul_rn(z[j], z[j]);
    for (int i = 8; i < 128; i += 8) {
#pragma unroll
        for (int j = 0; j < 8; ++j)
            r[j] = __fadd_rn(r[j], __fmul_rn(z[i + j], z[i + j]));
    }
    float t01 = __fadd_rn(r[0], r[1]), t23 = __fadd_rn(r[2], r[3]);
    float t45 = __fadd_rn(r[4], r[5]), t67 = __fadd_rn(r[6], r[7]);
    return __fadd_rn(__fadd_rn(t01, t23), __fadd_rn(t45, t67));
}
__device__ __forceinline__ float np_sqnorm256(const float* __restrict__ z) {
    return __fadd_rn(np_sqpair128(z), np_sqpair128(z + 128));
}

// ---------------- Stage 1: z32 = x @ W_pre^T + b_pre (np einsum f32 semantics) ----------------
// Packed f32 pairs; fp contract OFF keeps separate mul+add rounding (bit-exact, verified r2).
__global__ __launch_bounds__(256) void pre_quant(const float* __restrict__ x,
                                                 const float* __restrict__ Wpre,
                                                 const float* __restrict__ bpre,
                                                 float* __restrict__ z32) {
#pragma clang fp contract(off)
    __shared__ float xs[16][257];
    __shared__ float wt[32][258];   // [c][e]
    int n0 = blockIdx.x * 16;
    int b = n0 >> 8, pix0 = n0 & 255;
    int t = threadIdx.x;
#pragma unroll
    for (int i = 0; i < 16; ++i) {
        int f = t + i * 256;
        int c = f >> 4, p = f & 15;
        xs[p][c] = x[(size_t)b * 65536 + (size_t)c * 256 + pix0 + p];
    }
    int p = t & 15, eb = (t >> 4) * 16;
    f32x2 acc[8];
#pragma unroll
    for (int k = 0; k < 8; ++k) acc[k] = (f32x2){0.0f, 0.0f};

    for (int c0 = 0; c0 < 256; c0 += 32) {
        __syncthreads();
#pragma unroll
        for (int i = 0; i < 32; ++i) {
            int f = t + i * 256;
            int c = f & 31, e = f >> 5;
            wt[c][e] = Wpre[(size_t)e * 256 + c0 + c];
        }
        __syncthreads();
        for (int c = 0; c < 32; ++c) {
            float xv = xs[p][c0 + c];
            f32x2 xv2 = {xv, xv};
#pragma unroll
            for (int k = 0; k < 8; ++k) {
                f32x2 w2 = *(const f32x2*)&wt[c][eb + 2 * k];
                f32x2 m = w2 * xv2;        // v_(pk_)mul, rounded
                acc[k] = acc[k] + m;       // v_(pk_)add, rounded — no FMA (contract off)
            }
        }
    }
#pragma unroll
    for (int k = 0; k < 8; ++k) {
        f32x2 b2 = *(const f32x2*)&bpre[eb + 2 * k];
        *(f32x2*)&z32[(size_t)(n0 + p) * 256 + eb + 2 * k] = acc[k] + b2;
    }
}

// ---------------- norms (+ screening threshold) ----------------
__global__ __launch_bounds__(256) void row_norms_thr(const float* __restrict__ z32,
                                                     float* __restrict__ A32,
                                                     float* __restrict__ thr) {
    int n = blockIdx.x * 256 + threadIdx.x;
    float a = np_sqnorm256(z32 + (size_t)n * 256);
    A32[n] = a;
    // sigma = ||z|| / (8192*sqrt(3)); thr = 2.75*sigma - 1e-6 (see analysis)
    thr[n] = 2.75f * sqrtf(a) * 7.0466e-5f - 1e-6f;
}
__global__ __launch_bounds__(256) void cb_norms(const float* __restrict__ cb,
                                                float* __restrict__ C32) {
    int v = blockIdx.x * 256 + threadIdx.x;
    C32[v] = np_sqnorm256(cb + (size_t)v * 256);
}

// ---------------- fragment-layout bf16 builders ----------------
// fragment flat id = (tile16*8 + ks)*64 + lane; holds M[tile16*16 + (lane&15)][ks*32+(lane>>4)*8 .. +7]
__global__ __launch_bounds__(256) void build_frag(const float* __restrict__ src,
                                                  unsigned short* __restrict__ dst) {
    int gid = blockIdx.x * 256 + threadIdx.x;
    int l = gid & 63, ks = (gid >> 6) & 7, tile = gid >> 9;
    int row = tile * 16 + (l & 15);
    int k = ks * 32 + (l >> 4) * 8;
    const float* s = src + (size_t)row * 256 + k;
    float4 a = *(const float4*)s, b = *(const float4*)(s + 4);
    u16x8 o;
    o[0] = f2bf(a.x); o[1] = f2bf(a.y); o[2] = f2bf(a.z); o[3] = f2bf(a.w);
    o[4] = f2bf(b.x); o[5] = f2bf(b.y); o[6] = f2bf(b.z); o[7] = f2bf(b.w);
    *((u16x8*)dst + gid) = o;
}

// ---------------- Stage 2: MFMA screen, threshold append ----------------
// Block: 1024 thr = 16 waves, 64 rows, full V. Wave (g,h): g=w>>3 row-half (32 rows),
// h=w&7 v-16-tile within the 128 staged v. 64 phases x 128 v, LDS double-buffered.
__global__ __launch_bounds__(1024, 4) void screen(const unsigned short* __restrict__ zbf,
                                                  const unsigned short* __restrict__ cbf,
                                                  const float* __restrict__ C32,
                                                  const float* __restrict__ thr,
                                                  int* __restrict__ cnt,
                                                  int* __restrict__ cand) {
    __shared__ __align__(16) char lds[2][65536];
    int t = threadIdx.x;
    int w = t >> 6, l = t & 63;
    int g = w >> 3, h = w & 7;
    int rb = blockIdx.x * 64 + g * 32;

    // z fragments for the wave's two 16-row tiles
    bf16x8 zf[2][8];
#pragma unroll
    for (int tile = 0; tile < 2; ++tile)
#pragma unroll
        for (int ks = 0; ks < 8; ++ks) {
            size_t idx = ((size_t)((rb >> 4) + tile) * 8 + ks) * 64 + l;
            zf[tile][ks] = *((const bf16x8*)zbf + idx);
        }
    float thr0 = thr[rb + (l & 15)];
    float thr1 = thr[rb + 16 + (l & 15)];

    // prologue: stage phase 0
    {
        const char* src = (const char*)cbf;
#pragma unroll
        for (int q = 0; q < 4; ++q)
            gload_lds16(src + q * 16384 + t * 16, &lds[0][0] + q * 16384 + t * 16);
    }
    __syncthreads();

    for (int p = 0; p < 64; ++p) {
        int cur = p & 1;
        if (p < 63) {
            const char* src = (const char*)cbf + (size_t)(p + 1) * 65536;
            char* dst = &lds[cur ^ 1][0];
#pragma unroll
            for (int q = 0; q < 4; ++q)
                gload_lds16(src + q * 16384 + t * 16, dst + q * 16384 + t * 16);
        }
        f32x4 a0 = {0.f, 0.f, 0.f, 0.f}, a1 = {0.f, 0.f, 0.f, 0.f};
        const char* buf = &lds[cur][0];
#pragma unroll
        for (int ks = 0; ks < 8; ++ks) {
            bf16x8 af = *(const bf16x8*)(buf + (((h * 8 + ks) * 64) + l) * 16);
            a0 = __builtin_amdgcn_mfma_f32_16x16x32_bf16(af, zf[0][ks], a0, 0, 0, 0);
            a1 = __builtin_amdgcn_mfma_f32_16x16x32_bf16(af, zf[1][ks], a1, 0, 0, 0);
        }
        int v0 = p * 128 + h * 16 + (l >> 4) * 4;
        float4 c4 = *(const float4*)&C32[v0];
#pragma unroll
        for (int j = 0; j < 4; ++j) {
            float cv = (j == 0) ? c4.x : (j == 1) ? c4.y : (j == 2) ? c4.z : c4.w;
            float s0 = __fmaf_rn(-0.5f, cv, a0[j]);
            float s1 = __fmaf_rn(-0.5f, cv, a1[j]);
            if (s0 > thr0) {
                int r = rb + (l & 15);
                int slot = atomicAdd(&cnt[r], 1);
                if (slot < 64) cand[(size_t)r * 64 + slot] = v0 + j;
            }
            if (s1 > thr1) {
                int r = rb + 16 + (l & 15);
                int slot = atomicAdd(&cnt[r], 1);
                if (slot < 64) cand[(size_t)r * 64 + slot] = v0 + j;
            }
        }
        __syncthreads();
    }
}

// ---------------- Stage 3: exact np-f32 re-rank (order-independent) ----------------
__global__ __launch_bounds__(256) void rerank(const float* __restrict__ z32,
                                              const float* __restrict__ cb,
                                              const float* __restrict__ A32,
                                              const float* __restrict__ C32,
                                              const int* __restrict__ cand,
                                              const int* __restrict__ cnt,
                                              int* __restrict__ tok_i,
                                              float* __restrict__ tok_f) {
    int row = blockIdx.x * 4 + (threadIdx.x >> 6);
    int l = threadIdx.x & 63;
    int n = cnt[row]; if (n > 64) n = 64;
    float d = 3.4e38f; int v = 0x7fffffff;
    if (l < n) {
        v = cand[(size_t)row * 64 + l];
        const float* zr = z32 + (size_t)row * 256;
        const float* cr = cb + (size_t)v * 256;
        float s = 0.0f;
#pragma unroll 8
        for (int k = 0; k < 256; ++k)
            s = __fmaf_rn(cr[k], zr[k], s);   // strictly ascending k (r2-verified chain)
        d = __fadd_rn(__fsub_rn(A32[row], __fmul_rn(2.0f, s)), C32[v]);
    }
#pragma unroll
    for (int off = 32; off > 0; off >>= 1) {
        float d2 = __shfl_xor(d, off, 64);
        int   v2 = __shfl_xor(v, off, 64);
        if (d2 < d || (d2 == d && v2 < v)) { d = d2; v = v2; }
    }
    if (l == 0) { tok_i[row] = v; tok_f[row] = (float)v; }
}

// ---------------- Stage 4: rec = codebook[tok] @ W_post^T + b_post ----------------
__global__ __launch_bounds__(256) void post_quant(const float* __restrict__ cb,
                                                  const float* __restrict__ Wpost,
                                                  const float* __restrict__ bpost,
                                                  const int* __restrict__ tok,
                                                  float* __restrict__ rec) {
    __shared__ float zq[16][257];
    __shared__ float wt[256][33];
    int n0 = blockIdx.x * 16;
    int b = n0 >> 8, pix0 = n0 & 255;
    int t = threadIdx.x;
    for (int p = 0; p < 16; ++p) {
        int tv = tok[n0 + p];
        zq[p][t] = cb[(size_t)tv * 256 + t];
    }
    int p = t & 15, ccb = (t >> 4) * 16;
    float acc[16];
#pragma unroll
    for (int i = 0; i < 16; ++i) acc[i] = bpost[ccb + i];
    for (int e0 = 0; e0 < 256; e0 += 32) {
        __syncthreads();
#pragma unroll
        for (int i = 0; i < 32; ++i) {
            int f = t + i * 256;
            int cc = f >> 5, e = f & 31;
            wt[cc][e] = Wpost[(size_t)cc * 256 + e0 + e];
        }
        __syncthreads();
        for (int e = 0; e < 32; ++e) {
            float xz = zq[p][e0 + e];
#pragma unroll
            for (int i = 0; i < 16; ++i)
                acc[i] += wt[ccb + i][e] * xz;
        }
    }
#pragma unroll
    for (int i = 0; i < 16; ++i)
        rec[(size_t)b * 65536 + (size_t)(ccb + i) * 256 + pix0 + p] = acc[i];
}

// ---------------- Launch ----------------
extern "C" void kernel_launch(void* const* d_in, const int* in_sizes, int n_in,
                              void* d_out, int out_size, void* d_ws, size_t ws_size,
                              hipStream_t stream) {
    const float* x     = (const float*)d_in[0];
    const float* Wpre  = (const float*)d_in[1];
    const float* bpre  = (const float*)d_in[2];
    const float* cb    = (const float*)d_in[3];
    const float* Wpost = (const float*)d_in[4];
    const float* bpost = (const float*)d_in[5];

    float* out   = (float*)d_out;
    float* rec   = out;
    float* tok_f = out + 4194304;
    float* z32   = rec;   // z lives in rec region until post_quant overwrites it

    char* ws = (char*)d_ws;
    float*          A32   = (float*)(ws + 0);         // 64 KiB
    float*          C32   = (float*)(ws + 65536);     // 32 KiB
    int*            tok_i = (int*)(ws + 98304);       // 64 KiB
    float*          thr   = (float*)(ws + 163840);    // 64 KiB
    int*            cnt   = (int*)(ws + 229376);      // 64 KiB
    int*            cand  = (int*)(ws + 294912);      // 4 MiB
    unsigned short* zbf   = (unsigned short*)(ws + 4489216);   // 8 MiB
    unsigned short* cbf   = (unsigned short*)(ws + 12877824);  // 4 MiB

    pre_quant<<<NPIX / 16, 256, 0, stream>>>(x, Wpre, bpre, z32);
    row_norms_thr<<<NPIX / 256, 256, 0, stream>>>(z32, A32, thr);
    cb_norms<<<VDIM / 256, 256, 0, stream>>>(cb, C32);
    build_frag<<<(NPIX / 16) * 8 * 64 / 256, 256, 0, stream>>>(z32, zbf);
    build_frag<<<(VDIM / 16) * 8 * 64 / 256, 256, 0, stream>>>(cb, cbf);
    hipMemsetAsync(cnt, 0, NPIX * sizeof(int), stream);
    screen<<<NPIX / 64, 1024, 0, stream>>>(zbf, cbf, C32, thr, cnt, cand);
    rerank<<<NPIX / 4, 256, 0, stream>>>(z32, cb, A32, C32, cand, cnt, tok_i, tok_f);
    post_quant<<<NPIX / 16, 256, 0, stream>>>(cb, Wpost, bpost, tok_i, rec);
}

// Round 5
// 378.631 us; speedup vs baseline: 8.3385x; 1.4449x over previous
//
#include <hip/hip_runtime.h>
#include <cstdint>
#include <cstddef>

#define EDIM 256
#define VDIM 8192
#define NPIX 16384

typedef __attribute__((ext_vector_type(8))) short          bf16x8;
typedef __attribute__((ext_vector_type(8))) unsigned short u16x8;
typedef __attribute__((ext_vector_type(4))) float          f32x4;
typedef __attribute__((ext_vector_type(2))) float          f32x2;

// RNE float->bf16
__device__ __forceinline__ unsigned short f2bf(float x) {
    unsigned int u = __float_as_uint(x);
    return (unsigned short)((u + 0x7fffu + ((u >> 16) & 1u)) >> 16);
}

__device__ __forceinline__ void gload_lds16(const void* gsrc, void* ldst) {
#if defined(__has_builtin) && __has_builtin(__builtin_amdgcn_global_load_lds)
    __builtin_amdgcn_global_load_lds(
        (const __attribute__((address_space(1))) unsigned int*)gsrc,
        (__attribute__((address_space(3))) unsigned int*)ldst, 16, 0, 0);
#else
    *(float4*)ldst = *(const float4*)gsrc;   // correct fallback (slower)
#endif
}

// ---------- numpy pairwise sum-of-squares (exact semantics, verified r2) ----------
__device__ __forceinline__ float np_sqpair128(const float* __restrict__ z) {
    float r[8];
#pragma unroll
    for (int j = 0; j < 8; ++j) r[j] = __fmul_rn(z[j], z[j]);
    for (int i = 8; i < 128; i += 8) {
#pragma unroll
        for (int j = 0; j < 8; ++j)
            r[j] = __fadd_rn(r[j], __fmul_rn(z[i + j], z[i + j]));
    }
    float t01 = __fadd_rn(r[0], r[1]), t23 = __fadd_rn(r[2], r[3]);
    float t45 = __fadd_rn(r[4], r[5]), t67 = __fadd_rn(r[6], r[7]);
    return __fadd_rn(__fadd_rn(t01, t23), __fadd_rn(t45, t67));
}
__device__ __forceinline__ float np_sqnorm256(const float* __restrict__ z) {
    return __fadd_rn(np_sqpair128(z), np_sqpair128(z + 128));
}

// ---------------- Stage 1: z32 = x @ W_pre^T + b_pre (np einsum f32 semantics) ----------------
// Block = 32 pixels, 256 thr; thread tile = 4 pix x 8 e. Per element:
// acc = rn(acc + rn(x*w)) ascending c, then rn(acc + b) — bit-exact (r2/r4-verified chain).
__global__ __launch_bounds__(256) void pre_quant(const float* __restrict__ x,
                                                 const float* __restrict__ Wpre,
                                                 const float* __restrict__ bpre,
                                                 float* __restrict__ z32) {
#pragma clang fp contract(off)
    __shared__ float xs[32][36];    // [c][pix], row 144 B (16B-aligned)
    __shared__ float wt[32][260];   // [c][e],   row 1040 B (16B-aligned)
    int n0 = blockIdx.x * 32;
    int b = n0 >> 8, pix0 = n0 & 255;
    int t = threadIdx.x;
    int ep = t & 31, pg = t >> 5;   // e-base = ep*8, pix-base = pg*4

    f32x2 acc[4][4];                // [pix][e-pair]
#pragma unroll
    for (int pi = 0; pi < 4; ++pi)
#pragma unroll
        for (int j = 0; j < 4; ++j) acc[pi][j] = (f32x2){0.f, 0.f};

    for (int c0 = 0; c0 < 256; c0 += 32) {
        __syncthreads();
        {   // xs chunk: [32 c][32 pix]; thread: cc=t>>3, pix (t&7)*4..+3 (coalesced)
            int cc = t >> 3, pp = (t & 7) * 4;
            *(float4*)&xs[cc][pp] =
                *(const float4*)&x[(size_t)b * 65536 + (size_t)(c0 + cc) * 256 + pix0 + pp];
        }
        {   // wt chunk: thread t = e-row, reads Wpre[t][c0..c0+31], transposes into LDS
            const float* wr = Wpre + (size_t)t * 256 + c0;
#pragma unroll
            for (int i = 0; i < 32; i += 4) {
                float4 v = *(const float4*)&wr[i];
                wt[i + 0][t] = v.x; wt[i + 1][t] = v.y;
                wt[i + 2][t] = v.z; wt[i + 3][t] = v.w;
            }
        }
        __syncthreads();
#pragma unroll 8
        for (int cc = 0; cc < 32; ++cc) {
            float4 xv = *(const float4*)&xs[cc][pg * 4];            // broadcast
            float4 wa = *(const float4*)&wt[cc][ep * 8];            // balanced b128
            float4 wb = *(const float4*)&wt[cc][ep * 8 + 4];
            f32x2 w0 = {wa.x, wa.y}, w1 = {wa.z, wa.w};
            f32x2 w2 = {wb.x, wb.y}, w3 = {wb.z, wb.w};
            float xa[4] = {xv.x, xv.y, xv.z, xv.w};
#pragma unroll
            for (int pi = 0; pi < 4; ++pi) {
                f32x2 xsp = {xa[pi], xa[pi]};
                acc[pi][0] = acc[pi][0] + w0 * xsp;   // pk_mul then pk_add (contract off)
                acc[pi][1] = acc[pi][1] + w1 * xsp;
                acc[pi][2] = acc[pi][2] + w2 * xsp;
                acc[pi][3] = acc[pi][3] + w3 * xsp;
            }
        }
    }
    f32x2 b2[4];
#pragma unroll
    for (int j = 0; j < 4; ++j) b2[j] = *(const f32x2*)&bpre[ep * 8 + 2 * j];
#pragma unroll
    for (int pi = 0; pi < 4; ++pi) {
        f32x2 o[4];
#pragma unroll
        for (int j = 0; j < 4; ++j) o[j] = acc[pi][j] + b2[j];
        float* dst = &z32[(size_t)(n0 + pg * 4 + pi) * 256 + ep * 8];
        *(float4*)&dst[0] = *(float4*)&o[0];
        *(float4*)&dst[4] = *(float4*)&o[2];
    }
}

// ---------------- norms (+ screening threshold) ----------------
__global__ __launch_bounds__(256) void row_norms_thr(const float* __restrict__ z32,
                                                     float* __restrict__ A32,
                                                     float* __restrict__ thr) {
    int n = blockIdx.x * 256 + threadIdx.x;
    float a = np_sqnorm256(z32 + (size_t)n * 256);
    A32[n] = a;
    thr[n] = 2.75f * sqrtf(a) * 7.0466e-5f - 1e-6f;
}
__global__ __launch_bounds__(256) void cb_norms(const float* __restrict__ cb,
                                                float* __restrict__ C32) {
    int v = blockIdx.x * 256 + threadIdx.x;
    C32[v] = np_sqnorm256(cb + (size_t)v * 256);
}

// ---------------- fragment-layout bf16 builders ----------------
__global__ __launch_bounds__(256) void build_frag(const float* __restrict__ src,
                                                  unsigned short* __restrict__ dst) {
    int gid = blockIdx.x * 256 + threadIdx.x;
    int l = gid & 63, ks = (gid >> 6) & 7, tile = gid >> 9;
    int row = tile * 16 + (l & 15);
    int k = ks * 32 + (l >> 4) * 8;
    const float* s = src + (size_t)row * 256 + k;
    float4 a = *(const float4*)s, b = *(const float4*)(s + 4);
    u16x8 o;
    o[0] = f2bf(a.x); o[1] = f2bf(a.y); o[2] = f2bf(a.z); o[3] = f2bf(a.w);
    o[4] = f2bf(b.x); o[5] = f2bf(b.y); o[6] = f2bf(b.z); o[7] = f2bf(b.w);
    *((u16x8*)dst + gid) = o;
}

// ---------------- Stage 2: MFMA screen, threshold append (r4-validated) ----------------
__global__ __launch_bounds__(1024, 4) void screen(const unsigned short* __restrict__ zbf,
                                                  const unsigned short* __restrict__ cbf,
                                                  const float* __restrict__ C32,
                                                  const float* __restrict__ thr,
                                                  int* __restrict__ cnt,
                                                  int* __restrict__ cand) {
    __shared__ __align__(16) char lds[2][65536];
    int t = threadIdx.x;
    int w = t >> 6, l = t & 63;
    int g = w >> 3, h = w & 7;
    int rb = blockIdx.x * 64 + g * 32;

    bf16x8 zf[2][8];
#pragma unroll
    for (int tile = 0; tile < 2; ++tile)
#pragma unroll
        for (int ks = 0; ks < 8; ++ks) {
            size_t idx = ((size_t)((rb >> 4) + tile) * 8 + ks) * 64 + l;
            zf[tile][ks] = *((const bf16x8*)zbf + idx);
        }
    float thr0 = thr[rb + (l & 15)];
    float thr1 = thr[rb + 16 + (l & 15)];

    {
        const char* src = (const char*)cbf;
#pragma unroll
        for (int q = 0; q < 4; ++q)
            gload_lds16(src + q * 16384 + t * 16, &lds[0][0] + q * 16384 + t * 16);
    }
    __syncthreads();

    for (int p = 0; p < 64; ++p) {
        int cur = p & 1;
        if (p < 63) {
            const char* src = (const char*)cbf + (size_t)(p + 1) * 65536;
            char* dst = &lds[cur ^ 1][0];
#pragma unroll
            for (int q = 0; q < 4; ++q)
                gload_lds16(src + q * 16384 + t * 16, dst + q * 16384 + t * 16);
        }
        f32x4 a0 = {0.f, 0.f, 0.f, 0.f}, a1 = {0.f, 0.f, 0.f, 0.f};
        const char* buf = &lds[cur][0];
#pragma unroll
        for (int ks = 0; ks < 8; ++ks) {
            bf16x8 af = *(const bf16x8*)(buf + (((h * 8 + ks) * 64) + l) * 16);
            a0 = __builtin_amdgcn_mfma_f32_16x16x32_bf16(af, zf[0][ks], a0, 0, 0, 0);
            a1 = __builtin_amdgcn_mfma_f32_16x16x32_bf16(af, zf[1][ks], a1, 0, 0, 0);
        }
        int v0 = p * 128 + h * 16 + (l >> 4) * 4;
        float4 c4 = *(const float4*)&C32[v0];
#pragma unroll
        for (int j = 0; j < 4; ++j) {
            float cv = (j == 0) ? c4.x : (j == 1) ? c4.y : (j == 2) ? c4.z : c4.w;
            float s0 = __fmaf_rn(-0.5f, cv, a0[j]);
            float s1 = __fmaf_rn(-0.5f, cv, a1[j]);
            if (s0 > thr0) {
                int r = rb + (l & 15);
                int slot = atomicAdd(&cnt[r], 1);
                if (slot < 64) cand[(size_t)r * 64 + slot] = v0 + j;
            }
            if (s1 > thr1) {
                int r = rb + 16 + (l & 15);
                int slot = atomicAdd(&cnt[r], 1);
                if (slot < 64) cand[(size_t)r * 64 + slot] = v0 + j;
            }
        }
        __syncthreads();
    }
}

// ---------------- Stage 3: exact np-f32 re-rank (order-independent) ----------------
__global__ __launch_bounds__(256) void rerank(const float* __restrict__ z32,
                                              const float* __restrict__ cb,
                                              const float* __restrict__ A32,
                                              const float* __restrict__ C32,
                                              const int* __restrict__ cand,
                                              const int* __restrict__ cnt,
                                              int* __restrict__ tok_i,
                                              float* __restrict__ tok_f) {
    int row = blockIdx.x * 4 + (threadIdx.x >> 6);
    int l = threadIdx.x & 63;
    int n = cnt[row]; if (n > 64) n = 64;
    float d = 3.4e38f; int v = 0x7fffffff;
    if (l < n) {
        v = cand[(size_t)row * 64 + l];
        const float* zr = z32 + (size_t)row * 256;
        const float* cr = cb + (size_t)v * 256;
        float s = 0.0f;
#pragma unroll 8
        for (int k = 0; k < 256; ++k)
            s = __fmaf_rn(cr[k], zr[k], s);   // strictly ascending k (r2-verified chain)
        d = __fadd_rn(__fsub_rn(A32[row], __fmul_rn(2.0f, s)), C32[v]);
    }
#pragma unroll
    for (int off = 32; off > 0; off >>= 1) {
        float d2 = __shfl_xor(d, off, 64);
        int   v2 = __shfl_xor(v, off, 64);
        if (d2 < d || (d2 == d && v2 < v)) { d = d2; v = v2; }
    }
    if (l == 0) { tok_i[row] = v; tok_f[row] = (float)v; }
}

// ---------------- Stage 4: rec = codebook[tok] @ W_post^T + b_post ----------------
// Same geometry as pre_quant; FMA allowed (rec tolerance is loose — r1 fma version passed).
__global__ __launch_bounds__(256) void post_quant(const float* __restrict__ cb,
                                                  const float* __restrict__ Wpost,
                                                  const float* __restrict__ bpost,
                                                  const int* __restrict__ tok,
                                                  float* __restrict__ rec) {
    __shared__ float zq[256][36];   // [e][pix], 36 KB
    __shared__ float wt[32][260];   // [e-chunk][cout], 33 KB
    int n0 = blockIdx.x * 32;
    int b = n0 >> 8, pix0 = n0 & 255;
    int t = threadIdx.x;
    int ep = t & 31, pg = t >> 5;   // cout-base = ep*8, pix-base = pg*4

    {   // gather codebook rows: thread: pix=t&31, e-range (t>>5)*32..+31 (128 B contiguous)
        int pix = t & 31, eg = t >> 5;
        int tv = tok[n0 + pix];
        const float* cr = cb + (size_t)tv * 256 + eg * 32;
#pragma unroll
        for (int i = 0; i < 32; ++i)
            zq[eg * 32 + i][pix] = cr[i];
    }

    f32x2 acc[8][2];   // [cout j][pix-pair]
#pragma unroll
    for (int j = 0; j < 8; ++j) { acc[j][0] = (f32x2){0.f, 0.f}; acc[j][1] = (f32x2){0.f, 0.f}; }

    for (int e0 = 0; e0 < 256; e0 += 32) {
        __syncthreads();   // also covers initial zq gather
        const float* wr = Wpost + (size_t)t * 256 + e0;   // thread t = cout row
#pragma unroll
        for (int i = 0; i < 32; i += 4) {
            float4 v = *(const float4*)&wr[i];
            wt[i + 0][t] = v.x; wt[i + 1][t] = v.y;
            wt[i + 2][t] = v.z; wt[i + 3][t] = v.w;
        }
        __syncthreads();
#pragma unroll 8
        for (int ee = 0; ee < 32; ++ee) {
            float4 zv = *(const float4*)&zq[e0 + ee][pg * 4];   // broadcast
            f32x2 zp0 = {zv.x, zv.y}, zp1 = {zv.z, zv.w};
            float4 wa = *(const float4*)&wt[ee][ep * 8];
            float4 wb = *(const float4*)&wt[ee][ep * 8 + 4];
            float wv[8] = {wa.x, wa.y, wa.z, wa.w, wb.x, wb.y, wb.z, wb.w};
#pragma unroll
            for (int j = 0; j < 8; ++j) {
                f32x2 ws = {wv[j], wv[j]};
                acc[j][0] = ws * zp0 + acc[j][0];   // pk_fma
                acc[j][1] = ws * zp1 + acc[j][1];
            }
        }
    }
#pragma unroll
    for (int j = 0; j < 8; ++j) {
        int cout = ep * 8 + j;
        float bv = bpost[cout];
        f32x2 bs = {bv, bv};
        f32x2 o0 = acc[j][0] + bs, o1 = acc[j][1] + bs;
        float4 ov = {o0[0], o0[1], o1[0], o1[1]};
        *(float4*)&rec[(size_t)b * 65536 + (size_t)cout * 256 + pix0 + pg * 4] = ov;
    }
}

// ---------------- Launch ----------------
extern "C" void kernel_launch(void* const* d_in, const int* in_sizes, int n_in,
                              void* d_out, int out_size, void* d_ws, size_t ws_size,
                              hipStream_t stream) {
    const float* x     = (const float*)d_in[0];
    const float* Wpre  = (const float*)d_in[1];
    const float* bpre  = (const float*)d_in[2];
    const float* cb    = (const float*)d_in[3];
    const float* Wpost = (const float*)d_in[4];
    const float* bpost = (const float*)d_in[5];

    float* out   = (float*)d_out;
    float* rec   = out;
    float* tok_f = out + 4194304;
    float* z32   = rec;   // z lives in rec region until post_quant overwrites it

    char* ws = (char*)d_ws;
    float*          A32   = (float*)(ws + 0);         // 64 KiB
    float*          C32   = (float*)(ws + 65536);     // 32 KiB
    int*            tok_i = (int*)(ws + 98304);       // 64 KiB
    float*          thr   = (float*)(ws + 163840);    // 64 KiB
    int*            cnt   = (int*)(ws + 229376);      // 64 KiB
    int*            cand  = (int*)(ws + 294912);      // 4 MiB
    unsigned short* zbf   = (unsigned short*)(ws + 4489216);   // 8 MiB
    unsigned short* cbf   = (unsigned short*)(ws + 12877824);  // 4 MiB

    pre_quant<<<NPIX / 32, 256, 0, stream>>>(x, Wpre, bpre, z32);
    row_norms_thr<<<NPIX / 256, 256, 0, stream>>>(z32, A32, thr);
    cb_norms<<<VDIM / 256, 256, 0, stream>>>(cb, C32);
    build_frag<<<(NPIX / 16) * 8 * 64 / 256, 256, 0, stream>>>(z32, zbf);
    build_frag<<<(VDIM / 16) * 8 * 64 / 256, 256, 0, stream>>>(cb, cbf);
    hipMemsetAsync(cnt, 0, NPIX * sizeof(int), stream);
    screen<<<NPIX / 64, 1024, 0, stream>>>(zbf, cbf, C32, thr, cnt, cand);
    rerank<<<NPIX / 4, 256, 0, stream>>>(z32, cb, A32, C32, cand, cnt, tok_i, tok_f);
    post_quant<<<NPIX / 32, 256, 0, stream>>>(cb, Wpost, bpost, tok_i, rec);
}

// Round 6
// 371.204 us; speedup vs baseline: 8.5054x; 1.0200x over previous
//
#include <hip/hip_runtime.h>
#include <cstdint>
#include <cstddef>

#define EDIM 256
#define VDIM 8192
#define NPIX 16384

typedef __attribute__((ext_vector_type(8))) short          bf16x8;
typedef __attribute__((ext_vector_type(8))) unsigned short u16x8;
typedef __attribute__((ext_vector_type(4))) float          f32x4;
typedef __attribute__((ext_vector_type(2))) float          f32x2;

// RNE float->bf16
__device__ __forceinline__ unsigned short f2bf(float x) {
    unsigned int u = __float_as_uint(x);
    return (unsigned short)((u + 0x7fffu + ((u >> 16) & 1u)) >> 16);
}

__device__ __forceinline__ void gload_lds16(const void* gsrc, void* ldst) {
#if defined(__has_builtin) && __has_builtin(__builtin_amdgcn_global_load_lds)
    __builtin_amdgcn_global_load_lds(
        (const __attribute__((address_space(1))) unsigned int*)gsrc,
        (__attribute__((address_space(3))) unsigned int*)ldst, 16, 0, 0);
#else
    *(float4*)ldst = *(const float4*)gsrc;
#endif
}

// ---------- numpy pairwise sum-of-squares (exact semantics, verified r2) ----------
__device__ __forceinline__ float np_sqpair128(const float* __restrict__ z) {
    float r[8];
#pragma unroll
    for (int j = 0; j < 8; ++j) r[j] = __fmul_rn(z[j], z[j]);
    for (int i = 8; i < 128; i += 8) {
#pragma unroll
        for (int j = 0; j < 8; ++j)
            r[j] = __fadd_rn(r[j], __fmul_rn(z[i + j], z[i + j]));
    }
    float t01 = __fadd_rn(r[0], r[1]), t23 = __fadd_rn(r[2], r[3]);
    float t45 = __fadd_rn(r[4], r[5]), t67 = __fadd_rn(r[6], r[7]);
    return __fadd_rn(__fadd_rn(t01, t23), __fadd_rn(t45, t67));
}

// ---------------- Stage 1 (FUSED): z32 + zbf frags + A32 + thr ----------------
// np einsum f32 semantics: per element acc = rn(acc + rn(x*w)) ascending c, then rn(acc+b).
// Thread channel map: e in {2*ep + 64*j, +1} (lane stride 2 dwords in LDS -> 2-way, free).
__global__ __launch_bounds__(256) void pre_quant_fused(const float* __restrict__ x,
                                                       const float* __restrict__ Wpre,
                                                       const float* __restrict__ bpre,
                                                       float* __restrict__ z32,
                                                       unsigned short* __restrict__ zbf,
                                                       float* __restrict__ A32,
                                                       float* __restrict__ thr) {
#pragma clang fp contract(off)
    __shared__ float xs[32][36];
    __shared__ float wt[32][260];   // [c][e]; aliased as zs[32][260] in epilogue
    int n0 = blockIdx.x * 32;
    int b = n0 >> 8, pix0 = n0 & 255;
    int t = threadIdx.x;
    int ep = t & 31, pg = t >> 5;

    f32x2 acc[4][4];
#pragma unroll
    for (int pi = 0; pi < 4; ++pi)
#pragma unroll
        for (int j = 0; j < 4; ++j) acc[pi][j] = (f32x2){0.f, 0.f};

    for (int c0 = 0; c0 < 256; c0 += 32) {
        __syncthreads();
        {   int cc = t >> 3, pp = (t & 7) * 4;
            *(float4*)&xs[cc][pp] =
                *(const float4*)&x[(size_t)b * 65536 + (size_t)(c0 + cc) * 256 + pix0 + pp];
        }
        {   const float* wr = Wpre + (size_t)t * 256 + c0;
#pragma unroll
            for (int i = 0; i < 32; i += 4) {
                float4 v = *(const float4*)&wr[i];
                wt[i + 0][t] = v.x; wt[i + 1][t] = v.y;
                wt[i + 2][t] = v.z; wt[i + 3][t] = v.w;
            }
        }
        __syncthreads();
#pragma unroll 8
        for (int cc = 0; cc < 32; ++cc) {
            float4 xv = *(const float4*)&xs[cc][pg * 4];
            float xa[4] = {xv.x, xv.y, xv.z, xv.w};
            f32x2 wv[4];
#pragma unroll
            for (int j = 0; j < 4; ++j) wv[j] = *(const f32x2*)&wt[cc][2 * ep + 64 * j];
#pragma unroll
            for (int pi = 0; pi < 4; ++pi) {
                f32x2 xsp = {xa[pi], xa[pi]};
#pragma unroll
                for (int j = 0; j < 4; ++j) {
                    f32x2 m = wv[j] * xsp;      // pk_mul (rounded)
                    acc[pi][j] = acc[pi][j] + m; // pk_add (rounded) — contract off
                }
            }
        }
    }
    __syncthreads();   // all wt reads done before aliasing writes
    float* zs = &wt[0][0];   // [32][260]
    f32x2 b2[4];
#pragma unroll
    for (int j = 0; j < 4; ++j) b2[j] = *(const f32x2*)&bpre[2 * ep + 64 * j];
#pragma unroll
    for (int pi = 0; pi < 4; ++pi) {
        int row = pg * 4 + pi;
#pragma unroll
        for (int j = 0; j < 4; ++j) {
            f32x2 o = acc[pi][j] + b2[j];
            *(f32x2*)&z32[(size_t)(n0 + row) * 256 + 2 * ep + 64 * j] = o;
            *(f32x2*)&zs[row * 260 + 2 * ep + 64 * j] = o;
        }
    }
    __syncthreads();
    // fragment conversion: 1024 units, 4 per thread
#pragma unroll
    for (int q = 0; q < 4; ++q) {
        int uid = q * 256 + t;
        int l = uid & 63, ks = (uid >> 6) & 7, tile = uid >> 9;
        int rowl = tile * 16 + (l & 15), colb = ks * 32 + (l >> 4) * 8;
        const float* s = &zs[rowl * 260 + colb];
        float4 a = *(const float4*)s, bb = *(const float4*)(s + 4);
        u16x8 o;
        o[0] = f2bf(a.x); o[1] = f2bf(a.y); o[2] = f2bf(a.z); o[3] = f2bf(a.w);
        o[4] = f2bf(bb.x); o[5] = f2bf(bb.y); o[6] = f2bf(bb.z); o[7] = f2bf(bb.w);
        *((u16x8*)zbf + (((size_t)((n0 >> 4) + tile) * 8 + ks) * 64 + l)) = o;
    }
    // numpy-exact row norms + screening threshold
    if (t < 32) {
        float a = __fadd_rn(np_sqpair128(&zs[t * 260]), np_sqpair128(&zs[t * 260 + 128]));
        A32[n0 + t] = a;
        thr[n0 + t] = 2.75f * sqrtf(a) * 7.0466e-5f - 1e-6f;
    }
}

// ---------------- cb norms (np pairwise semantics) ----------------
__global__ __launch_bounds__(256) void cb_norms(const float* __restrict__ cb,
                                                float* __restrict__ C32) {
    int v = blockIdx.x * 256 + threadIdx.x;
    const float* r = cb + (size_t)v * 256;
    C32[v] = __fadd_rn(np_sqpair128(r), np_sqpair128(r + 128));
}

// ---------------- fragment-layout bf16 builder (codebook) ----------------
__global__ __launch_bounds__(256) void build_frag(const float* __restrict__ src,
                                                  unsigned short* __restrict__ dst) {
    int gid = blockIdx.x * 256 + threadIdx.x;
    int l = gid & 63, ks = (gid >> 6) & 7, tile = gid >> 9;
    int row = tile * 16 + (l & 15);
    int k = ks * 32 + (l >> 4) * 8;
    const float* s = src + (size_t)row * 256 + k;
    float4 a = *(const float4*)s, b = *(const float4*)(s + 4);
    u16x8 o;
    o[0] = f2bf(a.x); o[1] = f2bf(a.y); o[2] = f2bf(a.z); o[3] = f2bf(a.w);
    o[4] = f2bf(b.x); o[5] = f2bf(b.y); o[6] = f2bf(b.z); o[7] = f2bf(b.w);
    *((u16x8*)dst + gid) = o;
}

// ---------------- Stage 2: MFMA screen v2 ----------------
// Grid 256 = 32 rowblocks x 8 vblocks (vblk = bid&7 -> XCD-aligned cb slices).
// Block: 512 thr = 8 waves; wave owns 64 rows (zf[4][8], 128 VGPR), block = 512 rows x 1024 v.
// 8 phases x 128 v (64 KiB LDS, double-buffered). 4 MFMA per af read, MFMA-bound.
__global__ __launch_bounds__(512, 2) void screen(const unsigned short* __restrict__ zbf,
                                                 const unsigned short* __restrict__ cbf,
                                                 const float* __restrict__ C32,
                                                 const float* __restrict__ thr,
                                                 int* __restrict__ cnt,
                                                 int* __restrict__ cand) {
    __shared__ __align__(16) char lds[2][65536];
    int t = threadIdx.x, w = t >> 6, l = t & 63;
    int bid = blockIdx.x;
    int rowblk = bid >> 3, vblk = bid & 7;
    int rb = rowblk * 512 + w * 64;

    bf16x8 zf[4][8];
#pragma unroll
    for (int tt = 0; tt < 4; ++tt)
#pragma unroll
        for (int ks = 0; ks < 8; ++ks)
            zf[tt][ks] = *((const bf16x8*)zbf + (((size_t)((rb >> 4) + tt) * 8 + ks) * 64 + l));

    int   rown[4];
    float thrv[4];
#pragma unroll
    for (int tt = 0; tt < 4; ++tt) {
        rown[tt] = rb + tt * 16 + (l & 15);
        thrv[tt] = thr[rown[tt]];
    }

    const char* cbase = (const char*)cbf + (size_t)vblk * 524288;
    {   // prologue: stage phase 0
#pragma unroll
        for (int q = 0; q < 8; ++q)
            gload_lds16(cbase + q * 8192 + t * 16, &lds[0][0] + q * 8192 + t * 16);
    }
    __syncthreads();

    for (int p = 0; p < 8; ++p) {
        int cur = p & 1;
        if (p < 7) {
            const char* src = cbase + (size_t)(p + 1) * 65536;
            char* dst = &lds[cur ^ 1][0];
#pragma unroll
            for (int q = 0; q < 8; ++q)
                gload_lds16(src + q * 8192 + t * 16, dst + q * 8192 + t * 16);
        }
        const char* buf = &lds[cur][0];
#pragma unroll 2
        for (int vt = 0; vt < 8; ++vt) {
            f32x4 acc[4];
#pragma unroll
            for (int tt = 0; tt < 4; ++tt) acc[tt] = (f32x4){0.f, 0.f, 0.f, 0.f};
#pragma unroll
            for (int ks = 0; ks < 8; ++ks) {
                bf16x8 af = *(const bf16x8*)(buf + vt * 8192 + ks * 1024 + l * 16);
#pragma unroll
                for (int tt = 0; tt < 4; ++tt)
                    acc[tt] = __builtin_amdgcn_mfma_f32_16x16x32_bf16(af, zf[tt][ks], acc[tt], 0, 0, 0);
            }
            int v0 = vblk * 1024 + p * 128 + vt * 16 + (l >> 4) * 4;
            float4 c4 = *(const float4*)&C32[v0];
            float cv[4] = {c4.x, c4.y, c4.z, c4.w};
#pragma unroll
            for (int tt = 0; tt < 4; ++tt)
#pragma unroll
                for (int j = 0; j < 4; ++j) {
                    float s = __fmaf_rn(-0.5f, cv[j], acc[tt][j]);
                    if (s > thrv[tt]) {
                        int slot = atomicAdd(&cnt[rown[tt]], 1);
                        if (slot < 64) cand[(size_t)rown[tt] * 64 + slot] = v0 + j;
                    }
                }
        }
        __syncthreads();
    }
}

// ---------------- Stage 3: exact np-f32 re-rank (order-independent) ----------------
__global__ __launch_bounds__(256) void rerank(const float* __restrict__ z32,
                                              const float* __restrict__ cb,
                                              const float* __restrict__ A32,
                                              const float* __restrict__ C32,
                                              const int* __restrict__ cand,
                                              const int* __restrict__ cnt,
                                              int* __restrict__ tok_i,
                                              float* __restrict__ tok_f) {
    int row = blockIdx.x * 4 + (threadIdx.x >> 6);
    int l = threadIdx.x & 63;
    int n = cnt[row]; if (n > 64) n = 64;
    float d = 3.4e38f; int v = 0x7fffffff;
    if (l < n) {
        v = cand[(size_t)row * 64 + l];
        const float* zr = z32 + (size_t)row * 256;
        const float* cr = cb + (size_t)v * 256;
        float s = 0.0f;
#pragma unroll 8
        for (int k = 0; k < 256; ++k)
            s = __fmaf_rn(cr[k], zr[k], s);   // strictly ascending k (r2-verified chain)
        d = __fadd_rn(__fsub_rn(A32[row], __fmul_rn(2.0f, s)), C32[v]);
    }
#pragma unroll
    for (int off = 32; off > 0; off >>= 1) {
        float d2 = __shfl_xor(d, off, 64);
        int   v2 = __shfl_xor(v, off, 64);
        if (d2 < d || (d2 == d && v2 < v)) { d = d2; v = v2; }
    }
    if (l == 0) { tok_i[row] = v; tok_f[row] = (float)v; }
}

// ---------------- Stage 4: rec = codebook[tok] @ W_post^T + b_post ----------------
// Strided-pair channel map (2-way LDS, free); FMA allowed (rec tolerance loose).
__global__ __launch_bounds__(256) void post_quant(const float* __restrict__ cb,
                                                  const float* __restrict__ Wpost,
                                                  const float* __restrict__ bpost,
                                                  const int* __restrict__ tok,
                                                  float* __restrict__ rec) {
    __shared__ float zq[256][36];   // [e][pix]
    __shared__ float wt[32][260];   // [e-chunk][cout]
    int n0 = blockIdx.x * 32;
    int b = n0 >> 8, pix0 = n0 & 255;
    int t = threadIdx.x;
    int ep = t & 31, pg = t >> 5;

    {   int pix = t & 31, eg = t >> 5;
        int tv = tok[n0 + pix];
        const float* cr = cb + (size_t)tv * 256 + eg * 32;
#pragma unroll
        for (int i = 0; i < 32; ++i)
            zq[eg * 32 + i][pix] = cr[i];
    }

    f32x2 acc[8][2];   // [cout-slot s: cout=2ep+64*(s>>1)+(s&1)][pix-pair]
#pragma unroll
    for (int s = 0; s < 8; ++s) { acc[s][0] = (f32x2){0.f, 0.f}; acc[s][1] = (f32x2){0.f, 0.f}; }

    for (int e0 = 0; e0 < 256; e0 += 32) {
        __syncthreads();   // also covers initial zq gather
        const float* wr = Wpost + (size_t)t * 256 + e0;
#pragma unroll
        for (int i = 0; i < 32; i += 4) {
            float4 v = *(const float4*)&wr[i];
            wt[i + 0][t] = v.x; wt[i + 1][t] = v.y;
            wt[i + 2][t] = v.z; wt[i + 3][t] = v.w;
        }
        __syncthreads();
#pragma unroll 8
        for (int ee = 0; ee < 32; ++ee) {
            float4 zv = *(const float4*)&zq[e0 + ee][pg * 4];
            f32x2 zp0 = {zv.x, zv.y}, zp1 = {zv.z, zv.w};
#pragma unroll
            for (int J = 0; J < 4; ++J) {
                f32x2 wv = *(const f32x2*)&wt[ee][2 * ep + 64 * J];
                f32x2 w0 = {wv[0], wv[0]}, w1 = {wv[1], wv[1]};
                acc[2 * J + 0][0] = w0 * zp0 + acc[2 * J + 0][0];
                acc[2 * J + 0][1] = w0 * zp1 + acc[2 * J + 0][1];
                acc[2 * J + 1][0] = w1 * zp0 + acc[2 * J + 1][0];
                acc[2 * J + 1][1] = w1 * zp1 + acc[2 * J + 1][1];
            }
        }
    }
#pragma unroll
    for (int J = 0; J < 4; ++J)
#pragma unroll
        for (int c01 = 0; c01 < 2; ++c01) {
            int cout = 2 * ep + 64 * J + c01;
            float bv = bpost[cout];
            f32x2 bs = {bv, bv};
            f32x2 o0 = acc[2 * J + c01][0] + bs, o1 = acc[2 * J + c01][1] + bs;
            float4 ov = {o0[0], o0[1], o1[0], o1[1]};
            *(float4*)&rec[(size_t)b * 65536 + (size_t)cout * 256 + pix0 + pg * 4] = ov;
        }
}

// ---------------- Launch ----------------
extern "C" void kernel_launch(void* const* d_in, const int* in_sizes, int n_in,
                              void* d_out, int out_size, void* d_ws, size_t ws_size,
                              hipStream_t stream) {
    const float* x     = (const float*)d_in[0];
    const float* Wpre  = (const float*)d_in[1];
    const float* bpre  = (const float*)d_in[2];
    const float* cb    = (const float*)d_in[3];
    const float* Wpost = (const float*)d_in[4];
    const float* bpost = (const float*)d_in[5];

    float* out   = (float*)d_out;
    float* rec   = out;
    float* tok_f = out + 4194304;
    float* z32   = rec;   // z lives in rec region until post_quant overwrites it

    char* ws = (char*)d_ws;
    float*          A32   = (float*)(ws + 0);         // 64 KiB
    float*          C32   = (float*)(ws + 65536);     // 32 KiB
    int*            tok_i = (int*)(ws + 98304);       // 64 KiB
    float*          thr   = (float*)(ws + 163840);    // 64 KiB
    int*            cnt   = (int*)(ws + 229376);      // 64 KiB
    int*            cand  = (int*)(ws + 294912);      // 4 MiB
    unsigned short* zbf   = (unsigned short*)(ws + 4489216);   // 8 MiB
    unsigned short* cbf   = (unsigned short*)(ws + 12877824);  // 4 MiB

    pre_quant_fused<<<NPIX / 32, 256, 0, stream>>>(x, Wpre, bpre, z32, zbf, A32, thr);
    cb_norms<<<VDIM / 256, 256, 0, stream>>>(cb, C32);
    build_frag<<<(VDIM / 16) * 8 * 64 / 256, 256, 0, stream>>>(cb, cbf);
    hipMemsetAsync(cnt, 0, NPIX * sizeof(int), stream);
    screen<<<NPIX / 64, 512, 0, stream>>>(zbf, cbf, C32, thr, cnt, cand);
    rerank<<<NPIX / 4, 256, 0, stream>>>(z32, cb, A32, C32, cand, cnt, tok_i, tok_f);
    post_quant<<<NPIX / 32, 256, 0, stream>>>(cb, Wpost, bpost, tok_i, rec);
}

// Round 7
// 339.928 us; speedup vs baseline: 9.2879x; 1.0920x over previous
//
#include <hip/hip_runtime.h>
#include <cstdint>
#include <cstddef>

#define EDIM 256
#define VDIM 8192
#define NPIX 16384

typedef __attribute__((ext_vector_type(8))) short          bf16x8;
typedef __attribute__((ext_vector_type(8))) unsigned short u16x8;
typedef __attribute__((ext_vector_type(4))) float          f32x4;
typedef __attribute__((ext_vector_type(2))) float          f32x2;

// RNE float->bf16
__device__ __forceinline__ unsigned short f2bf(float x) {
    unsigned int u = __float_as_uint(x);
    return (unsigned short)((u + 0x7fffu + ((u >> 16) & 1u)) >> 16);
}

__device__ __forceinline__ void gload_lds16(const void* gsrc, void* ldst) {
#if defined(__has_builtin) && __has_builtin(__builtin_amdgcn_global_load_lds)
    __builtin_amdgcn_global_load_lds(
        (const __attribute__((address_space(1))) unsigned int*)gsrc,
        (__attribute__((address_space(3))) unsigned int*)ldst, 16, 0, 0);
#else
    *(float4*)ldst = *(const float4*)gsrc;
#endif
}

// ---------- numpy pairwise sum-of-squares (exact semantics, verified r2) ----------
__device__ __forceinline__ float np_sqpair128(const float* __restrict__ z) {
    float r[8];
#pragma unroll
    for (int j = 0; j < 8; ++j) r[j] = __fmul_rn(z[j], z[j]);
    for (int i = 8; i < 128; i += 8) {
#pragma unroll
        for (int j = 0; j < 8; ++j)
            r[j] = __fadd_rn(r[j], __fmul_rn(z[i + j], z[i + j]));
    }
    float t01 = __fadd_rn(r[0], r[1]), t23 = __fadd_rn(r[2], r[3]);
    float t45 = __fadd_rn(r[4], r[5]), t67 = __fadd_rn(r[6], r[7]);
    return __fadd_rn(__fadd_rn(t01, t23), __fadd_rn(t45, t67));
}

// ---------------- Stage 1 (FUSED): z32 + zbf frags + A32 + thr ----------------
__global__ __launch_bounds__(256) void pre_quant_fused(const float* __restrict__ x,
                                                       const float* __restrict__ Wpre,
                                                       const float* __restrict__ bpre,
                                                       float* __restrict__ z32,
                                                       unsigned short* __restrict__ zbf,
                                                       float* __restrict__ A32,
                                                       float* __restrict__ thr) {
#pragma clang fp contract(off)
    __shared__ float xs[32][36];
    __shared__ float wt[32][260];   // [c][e]; aliased as zs[32][260] in epilogue
    int n0 = blockIdx.x * 32;
    int b = n0 >> 8, pix0 = n0 & 255;
    int t = threadIdx.x;
    int ep = t & 31, pg = t >> 5;

    f32x2 acc[4][4];
#pragma unroll
    for (int pi = 0; pi < 4; ++pi)
#pragma unroll
        for (int j = 0; j < 4; ++j) acc[pi][j] = (f32x2){0.f, 0.f};

    for (int c0 = 0; c0 < 256; c0 += 32) {
        __syncthreads();
        {   int cc = t >> 3, pp = (t & 7) * 4;
            *(float4*)&xs[cc][pp] =
                *(const float4*)&x[(size_t)b * 65536 + (size_t)(c0 + cc) * 256 + pix0 + pp];
        }
        {   const float* wr = Wpre + (size_t)t * 256 + c0;
#pragma unroll
            for (int i = 0; i < 32; i += 4) {
                float4 v = *(const float4*)&wr[i];
                wt[i + 0][t] = v.x; wt[i + 1][t] = v.y;
                wt[i + 2][t] = v.z; wt[i + 3][t] = v.w;
            }
        }
        __syncthreads();
#pragma unroll 8
        for (int cc = 0; cc < 32; ++cc) {
            float4 xv = *(const float4*)&xs[cc][pg * 4];
            float xa[4] = {xv.x, xv.y, xv.z, xv.w};
            f32x2 wv[4];
#pragma unroll
            for (int j = 0; j < 4; ++j) wv[j] = *(const f32x2*)&wt[cc][2 * ep + 64 * j];
#pragma unroll
            for (int pi = 0; pi < 4; ++pi) {
                f32x2 xsp = {xa[pi], xa[pi]};
#pragma unroll
                for (int j = 0; j < 4; ++j) {
                    f32x2 m = wv[j] * xsp;       // pk_mul (rounded)
                    acc[pi][j] = acc[pi][j] + m;  // pk_add (rounded) — contract off
                }
            }
        }
    }
    __syncthreads();   // all wt reads done before aliasing writes
    float* zs = &wt[0][0];   // [32][260]
    f32x2 b2[4];
#pragma unroll
    for (int j = 0; j < 4; ++j) b2[j] = *(const f32x2*)&bpre[2 * ep + 64 * j];
#pragma unroll
    for (int pi = 0; pi < 4; ++pi) {
        int row = pg * 4 + pi;
#pragma unroll
        for (int j = 0; j < 4; ++j) {
            f32x2 o = acc[pi][j] + b2[j];
            *(f32x2*)&z32[(size_t)(n0 + row) * 256 + 2 * ep + 64 * j] = o;
            *(f32x2*)&zs[row * 260 + 2 * ep + 64 * j] = o;
        }
    }
    __syncthreads();
#pragma unroll
    for (int q = 0; q < 4; ++q) {
        int uid = q * 256 + t;
        int l = uid & 63, ks = (uid >> 6) & 7, tile = uid >> 9;
        int rowl = tile * 16 + (l & 15), colb = ks * 32 + (l >> 4) * 8;
        const float* s = &zs[rowl * 260 + colb];
        float4 a = *(const float4*)s, bb = *(const float4*)(s + 4);
        u16x8 o;
        o[0] = f2bf(a.x); o[1] = f2bf(a.y); o[2] = f2bf(a.z); o[3] = f2bf(a.w);
        o[4] = f2bf(bb.x); o[5] = f2bf(bb.y); o[6] = f2bf(bb.z); o[7] = f2bf(bb.w);
        *((u16x8*)zbf + (((size_t)((n0 >> 4) + tile) * 8 + ks) * 64 + l)) = o;
    }
    if (t < 32) {
        float a = __fadd_rn(np_sqpair128(&zs[t * 260]), np_sqpair128(&zs[t * 260 + 128]));
        A32[n0 + t] = a;
        thr[n0 + t] = 2.75f * sqrtf(a) * 7.0466e-5f - 1e-6f;
    }
}

// ---------------- cb norms (np pairwise semantics) ----------------
__global__ __launch_bounds__(256) void cb_norms(const float* __restrict__ cb,
                                                float* __restrict__ C32) {
    int v = blockIdx.x * 256 + threadIdx.x;
    const float* r = cb + (size_t)v * 256;
    C32[v] = __fadd_rn(np_sqpair128(r), np_sqpair128(r + 128));
}

// ---------------- fragment-layout bf16 builder (codebook) ----------------
__global__ __launch_bounds__(256) void build_frag(const float* __restrict__ src,
                                                  unsigned short* __restrict__ dst) {
    int gid = blockIdx.x * 256 + threadIdx.x;
    int l = gid & 63, ks = (gid >> 6) & 7, tile = gid >> 9;
    int row = tile * 16 + (l & 15);
    int k = ks * 32 + (l >> 4) * 8;
    const float* s = src + (size_t)row * 256 + k;
    float4 a = *(const float4*)s, b = *(const float4*)(s + 4);
    u16x8 o;
    o[0] = f2bf(a.x); o[1] = f2bf(a.y); o[2] = f2bf(a.z); o[3] = f2bf(a.w);
    o[4] = f2bf(b.x); o[5] = f2bf(b.y); o[6] = f2bf(b.z); o[7] = f2bf(b.w);
    *((u16x8*)dst + gid) = o;
}

// ---------------- Stage 2: MFMA screen v3 (register-pinned zf) ----------------
// Grid 256: rowblk = bid % 32, vblk = bid >> 5 (XCD = bid%8 = rowblk%8 -> 32 blocks
// per XCD share 1 MiB of zbf). Block: 512 thr = 8 waves; wave = 64 rows (zf[4][8],
// 128 VGPR, asm-pinned); block = 512 rows x 1024 v; 8 phases x 128 v, dbuf LDS.
__global__ __launch_bounds__(512, 2) void screen(const unsigned short* __restrict__ zbf,
                                                 const unsigned short* __restrict__ cbf,
                                                 const float* __restrict__ C32,
                                                 const float* __restrict__ thr,
                                                 int* __restrict__ cnt,
                                                 int* __restrict__ cand) {
    __shared__ __align__(16) char lds[2][65536];
    int t = threadIdx.x, w = t >> 6, l = t & 63;
    int bid = blockIdx.x;
    int rowblk = bid & 31, vblk = bid >> 5;
    int rb = rowblk * 512 + w * 64;

    // z fragments: 32 x bf16x8 = 128 VGPR. The asm pin makes each value opaque so
    // the compiler cannot demote/rematerialize them inside the phase loop
    // (r5/r6 post-mortem: VGPR_Count 52/96 < frag footprint => spilled reloads).
    bf16x8 zf[4][8];
#pragma unroll
    for (int tt = 0; tt < 4; ++tt)
#pragma unroll
        for (int ks = 0; ks < 8; ++ks) {
            zf[tt][ks] = *((const bf16x8*)zbf + (((size_t)((rb >> 4) + tt) * 8 + ks) * 64 + l));
            asm volatile("" : "+v"(zf[tt][ks]));
        }

    int   rown[4];
    float thrv[4];
#pragma unroll
    for (int tt = 0; tt < 4; ++tt) {
        rown[tt] = rb + tt * 16 + (l & 15);
        thrv[tt] = thr[rown[tt]];
    }

    const char* cbase = (const char*)cbf + (size_t)vblk * 524288;
    {
#pragma unroll
        for (int q = 0; q < 8; ++q)
            gload_lds16(cbase + q * 8192 + t * 16, &lds[0][0] + q * 8192 + t * 16);
    }
    __syncthreads();

    for (int p = 0; p < 8; ++p) {
        int cur = p & 1;
        if (p < 7) {
            const char* src = cbase + (size_t)(p + 1) * 65536;
            char* dst = &lds[cur ^ 1][0];
#pragma unroll
            for (int q = 0; q < 8; ++q)
                gload_lds16(src + q * 8192 + t * 16, dst + q * 8192 + t * 16);
        }
        const char* buf = &lds[cur][0];
#pragma unroll 2
        for (int vt = 0; vt < 8; ++vt) {
            f32x4 acc[4];
#pragma unroll
            for (int tt = 0; tt < 4; ++tt) acc[tt] = (f32x4){0.f, 0.f, 0.f, 0.f};
#pragma unroll
            for (int ks = 0; ks < 8; ++ks) {
                bf16x8 af = *(const bf16x8*)(buf + vt * 8192 + ks * 1024 + l * 16);
#pragma unroll
                for (int tt = 0; tt < 4; ++tt)
                    acc[tt] = __builtin_amdgcn_mfma_f32_16x16x32_bf16(af, zf[tt][ks], acc[tt], 0, 0, 0);
            }
            int v0 = vblk * 1024 + p * 128 + vt * 16 + (l >> 4) * 4;
            float4 c4 = *(const float4*)&C32[v0];
            float cv[4] = {c4.x, c4.y, c4.z, c4.w};
#pragma unroll
            for (int tt = 0; tt < 4; ++tt)
#pragma unroll
                for (int j = 0; j < 4; ++j) {
                    float s = __fmaf_rn(-0.5f, cv[j], acc[tt][j]);
                    if (s > thrv[tt]) {
                        int slot = atomicAdd(&cnt[rown[tt]], 1);
                        if (slot < 64) cand[(size_t)rown[tt] * 64 + slot] = v0 + j;
                    }
                }
        }
        __syncthreads();
    }
}

// ---------------- Stage 3: exact np-f32 re-rank (order-independent) ----------------
__global__ __launch_bounds__(256) void rerank(const float* __restrict__ z32,
                                              const float* __restrict__ cb,
                                              const float* __restrict__ A32,
                                              const float* __restrict__ C32,
                                              const int* __restrict__ cand,
                                              const int* __restrict__ cnt,
                                              int* __restrict__ tok_i,
                                              float* __restrict__ tok_f) {
    int row = blockIdx.x * 4 + (threadIdx.x >> 6);
    int l = threadIdx.x & 63;
    int n = cnt[row]; if (n > 64) n = 64;
    float d = 3.4e38f; int v = 0x7fffffff;
    if (l < n) {
        v = cand[(size_t)row * 64 + l];
        const float* zr = z32 + (size_t)row * 256;
        const float* cr = cb + (size_t)v * 256;
        float s = 0.0f;
#pragma unroll 8
        for (int k = 0; k < 256; ++k)
            s = __fmaf_rn(cr[k], zr[k], s);   // strictly ascending k (r2-verified chain)
        d = __fadd_rn(__fsub_rn(A32[row], __fmul_rn(2.0f, s)), C32[v]);
    }
#pragma unroll
    for (int off = 32; off > 0; off >>= 1) {
        float d2 = __shfl_xor(d, off, 64);
        int   v2 = __shfl_xor(v, off, 64);
        if (d2 < d || (d2 == d && v2 < v)) { d = d2; v = v2; }
    }
    if (l == 0) { tok_i[row] = v; tok_f[row] = (float)v; }
}

// ---------------- Stage 4: rec = codebook[tok] @ W_post^T + b_post ----------------
__global__ __launch_bounds__(256) void post_quant(const float* __restrict__ cb,
                                                  const float* __restrict__ Wpost,
                                                  const float* __restrict__ bpost,
                                                  const int* __restrict__ tok,
                                                  float* __restrict__ rec) {
    __shared__ float zq[256][36];   // [e][pix]
    __shared__ float wt[32][260];   // [e-chunk][cout]
    int n0 = blockIdx.x * 32;
    int b = n0 >> 8, pix0 = n0 & 255;
    int t = threadIdx.x;
    int ep = t & 31, pg = t >> 5;

    {   int pix = t & 31, eg = t >> 5;
        int tv = tok[n0 + pix];
        const float* cr = cb + (size_t)tv * 256 + eg * 32;
#pragma unroll
        for (int i = 0; i < 32; ++i)
            zq[eg * 32 + i][pix] = cr[i];
    }

    f32x2 acc[8][2];
#pragma unroll
    for (int s = 0; s < 8; ++s) { acc[s][0] = (f32x2){0.f, 0.f}; acc[s][1] = (f32x2){0.f, 0.f}; }

    for (int e0 = 0; e0 < 256; e0 += 32) {
        __syncthreads();
        const float* wr = Wpost + (size_t)t * 256 + e0;
#pragma unroll
        for (int i = 0; i < 32; i += 4) {
            float4 v = *(const float4*)&wr[i];
            wt[i + 0][t] = v.x; wt[i + 1][t] = v.y;
            wt[i + 2][t] = v.z; wt[i + 3][t] = v.w;
        }
        __syncthreads();
#pragma unroll 8
        for (int ee = 0; ee < 32; ++ee) {
            float4 zv = *(const float4*)&zq[e0 + ee][pg * 4];
            f32x2 zp0 = {zv.x, zv.y}, zp1 = {zv.z, zv.w};
#pragma unroll
            for (int J = 0; J < 4; ++J) {
                f32x2 wv = *(const f32x2*)&wt[ee][2 * ep + 64 * J];
                f32x2 w0 = {wv[0], wv[0]}, w1 = {wv[1], wv[1]};
                acc[2 * J + 0][0] = w0 * zp0 + acc[2 * J + 0][0];
                acc[2 * J + 0][1] = w0 * zp1 + acc[2 * J + 0][1];
                acc[2 * J + 1][0] = w1 * zp0 + acc[2 * J + 1][0];
                acc[2 * J + 1][1] = w1 * zp1 + acc[2 * J + 1][1];
            }
        }
    }
#pragma unroll
    for (int J = 0; J < 4; ++J)
#pragma unroll
        for (int c01 = 0; c01 < 2; ++c01) {
            int cout = 2 * ep + 64 * J + c01;
            float bv = bpost[cout];
            f32x2 bs = {bv, bv};
            f32x2 o0 = acc[2 * J + c01][0] + bs, o1 = acc[2 * J + c01][1] + bs;
            float4 ov = {o0[0], o0[1], o1[0], o1[1]};
            *(float4*)&rec[(size_t)b * 65536 + (size_t)cout * 256 + pix0 + pg * 4] = ov;
        }
}

// ---------------- Launch ----------------
extern "C" void kernel_launch(void* const* d_in, const int* in_sizes, int n_in,
                              void* d_out, int out_size, void* d_ws, size_t ws_size,
                              hipStream_t stream) {
    const float* x     = (const float*)d_in[0];
    const float* Wpre  = (const float*)d_in[1];
    const float* bpre  = (const float*)d_in[2];
    const float* cb    = (const float*)d_in[3];
    const float* Wpost = (const float*)d_in[4];
    const float* bpost = (const float*)d_in[5];

    float* out   = (float*)d_out;
    float* rec   = out;
    float* tok_f = out + 4194304;
    float* z32   = rec;   // z lives in rec region until post_quant overwrites it

    char* ws = (char*)d_ws;
    float*          A32   = (float*)(ws + 0);         // 64 KiB
    float*          C32   = (float*)(ws + 65536);     // 32 KiB
    int*            tok_i = (int*)(ws + 98304);       // 64 KiB
    float*          thr   = (float*)(ws + 163840);    // 64 KiB
    int*            cnt   = (int*)(ws + 229376);      // 64 KiB
    int*            cand  = (int*)(ws + 294912);      // 4 MiB
    unsigned short* zbf   = (unsigned short*)(ws + 4489216);   // 8 MiB
    unsigned short* cbf   = (unsigned short*)(ws + 12877824);  // 4 MiB

    pre_quant_fused<<<NPIX / 32, 256, 0, stream>>>(x, Wpre, bpre, z32, zbf, A32, thr);
    cb_norms<<<VDIM / 256, 256, 0, stream>>>(cb, C32);
    build_frag<<<(VDIM / 16) * 8 * 64 / 256, 256, 0, stream>>>(cb, cbf);
    hipMemsetAsync(cnt, 0, NPIX * sizeof(int), stream);
    screen<<<256, 512, 0, stream>>>(zbf, cbf, C32, thr, cnt, cand);
    rerank<<<NPIX / 4, 256, 0, stream>>>(z32, cb, A32, C32, cand, cnt, tok_i, tok_f);
    post_quant<<<NPIX / 32, 256, 0, stream>>>(cb, Wpost, bpost, tok_i, rec);
}